// Round 14
// baseline (388.258 us; speedup 1.0000x reference)
//
#include <hip/hip_runtime.h>
#include <hip/hip_bf16.h>

typedef __attribute__((ext_vector_type(4))) float  f32x4;
typedef __attribute__((ext_vector_type(8))) short  short8;
typedef __attribute__((ext_vector_type(4))) short  short4v;

__device__ __forceinline__ unsigned short f32_to_bf16(float f) {
    union { float f; unsigned u; } v; v.f = f;
    unsigned r = v.u + 0x7FFFu + ((v.u >> 16) & 1u);   // RNE
    return (unsigned short)(r >> 16);
}
__device__ __forceinline__ float bf16_to_f32(unsigned short h) {
    union { unsigned u; float f; } v; v.u = ((unsigned)h) << 16; return v.f;
}
__device__ __forceinline__ void gload_lds16(const void* g, void* l) {
    __builtin_amdgcn_global_load_lds(
        (const __attribute__((address_space(1))) unsigned int*)g,
        (__attribute__((address_space(3))) unsigned int*)l,
        16, 0, 0);
}

// ---------------- merged transpose + fp32->bf16 convert (both inputs, one launch) -------------
// bid < WT_BLOCKS: W [2048][1000] -> Wt [1024][2048] ; else comp [2048][8192] -> compT [8192][2048]
#define WT_BLOCKS 512    /* (1024/64) * (2048/64) */

__global__ __launch_bounds__(256) void transpose_both(
    const float* __restrict__ W, unsigned short* __restrict__ Wt,
    const float* __restrict__ comp, unsigned short* __restrict__ compT) {
    __shared__ float tile[64][65];
    const int t = threadIdx.x;
    const float* src; unsigned short* dst;
    int R, Cin, Cpad, bx, by;
    if (blockIdx.x < WT_BLOCKS) {
        src = W; dst = Wt; R = 2048; Cin = 1000; Cpad = 1024;
        bx = blockIdx.x & 15; by = blockIdx.x >> 4;      // 16 x 32
    } else {
        src = comp; dst = compT; R = 2048; Cin = 8192; Cpad = 8192;
        int b = blockIdx.x - WT_BLOCKS;
        bx = b & 127; by = b >> 7;                       // 128 x 32
    }
    const int c0 = bx * 64, r0 = by * 64;
#pragma unroll
    for (int p = 0; p < 16; ++p) {
        int lin = p * 256 + t;
        int r = lin >> 6, c = lin & 63;
        float v = 0.f;
        if (c0 + c < Cin) v = src[(size_t)(r0 + r) * Cin + (c0 + c)];
        tile[r][c] = v;
    }
    __syncthreads();
    unsigned int* dst32 = (unsigned int*)dst;
#pragma unroll
    for (int p = 0; p < 8; ++p) {
        int lin = p * 256 + t;
        int c = lin >> 5;
        int rp = lin & 31;
        int cg = c0 + c;
        if (cg < Cpad) {
            unsigned lo = f32_to_bf16(tile[rp * 2][c]);
            unsigned hi = f32_to_bf16(tile[rp * 2 + 1][c]);
            dst32[((size_t)cg * R + r0) / 2 + rp] = lo | (hi << 16);
        }
    }
}

// ---------------- bias[c] = -sum_d mean[d] * Mt[c][d] ----------------
__global__ __launch_bounds__(256) void bias_kernel(
    const float* __restrict__ mean, const unsigned short* __restrict__ Mt,
    float* __restrict__ bias, int D) {
    const int c = blockIdx.x;
    const unsigned short* row = Mt + (size_t)c * D;
    float s = 0.f;
    for (int d0 = threadIdx.x * 8; d0 < D; d0 += 256 * 8) {
        short4v h0 = *(const short4v*)&row[d0];
        short4v h1 = *(const short4v*)&row[d0 + 4];
        f32x4  m0 = *(const f32x4*)&mean[d0];
        f32x4  m1 = *(const f32x4*)&mean[d0 + 4];
#pragma unroll
        for (int j = 0; j < 4; ++j) {
            s += bf16_to_f32((unsigned short)h0[j]) * m0[j];
            s += bf16_to_f32((unsigned short)h1[j]) * m1[j];
        }
    }
#pragma unroll
    for (int off = 32; off > 0; off >>= 1) s += __shfl_down(s, off);
    __shared__ float red[4];
    const int lane = threadIdx.x & 63, w = threadIdx.x >> 6;
    if (lane == 0) red[w] = s;
    __syncthreads();
    if (threadIdx.x == 0) bias[c] = -(red[0] + red[1] + red[2] + red[3]);
}

// ================= shared staging helpers (swizzle: byte ^= (row&7)<<4 in 128B rows) ===========
template<int P0, int P1>
__device__ __forceinline__ void stage_part(
    const unsigned short* __restrict__ g, int K, int k0,
    unsigned short* l, int tid) {
#pragma unroll
    for (int p = P0; p < P1; ++p) {
        unsigned lin = ((unsigned)p * 512 + (unsigned)tid) * 16u;
        unsigned row = lin >> 7;
        unsigned colb = (lin ^ ((row & 7u) << 4)) & 127u;
        gload_lds16((const char*)g + (size_t)row * K * 2 + (size_t)k0 * 2 + colb,
                    (char*)l + lin);
    }
}

__device__ __forceinline__ short8 lfrag(const unsigned short* base, unsigned row, unsigned cb) {
    unsigned lin = row * 128u + cb;
    unsigned b = lin ^ ((row & 7u) << 4);
    return *(const short8*)((const char*)base + b);
}

// ================= FAT: waves 0-7 pipelined GEMM1 (256x128, 3-buf) ; waves 8-15 convert ========
#define P_BM 256
#define P_BN 128
#define P_BK 64
#define ABUF 16384
#define BUFE 24576
#define P_LDS_BYTES (3 * BUFE * 2)

__global__ __launch_bounds__(1024) void fat_g1conv(
    const unsigned short* __restrict__ A, const unsigned short* __restrict__ Bt,
    unsigned short* __restrict__ C, int M, int N, int K,
    const float* __restrict__ feats, unsigned short* __restrict__ featsB) {
    extern __shared__ unsigned short lds[];
    const int bid = blockIdx.x;
    const int tid = threadIdx.x;
    const int NT = K / P_BK;                     // 32

    if (tid < 512) {
        const int x = bid & 7, i = bid >> 3;
        const int col0 = (x * 8 + (i >> 2)) * P_BN;
        const int row0 = (i & 3) * P_BM;
        const int w = tid >> 6, lane = tid & 63;
        const int wm = w >> 1, wn = w & 1;
        const int lr = lane & 15, hi = lane >> 4;
        const int arow = wm * 64 + lr;
        const int brow = wn * 64 + lr;

        const unsigned short* Ag = A + (size_t)row0 * K;
        const unsigned short* Bg = Bt + (size_t)col0 * K;

        f32x4 acc[4][4];
#pragma unroll
        for (int m = 0; m < 4; ++m)
#pragma unroll
            for (int n = 0; n < 4; ++n) acc[m][n] = (f32x4){0.f, 0.f, 0.f, 0.f};

        stage_part<0, 4>(Ag, K, 0, lds, tid);
        stage_part<0, 2>(Bg, K, 0, lds + ABUF, tid);
        stage_part<0, 4>(Ag, K, P_BK, lds + BUFE, tid);
        stage_part<0, 2>(Bg, K, P_BK, lds + BUFE + ABUF, tid);

        for (int t = 0; t < NT; ++t) {
            if (t + 1 < NT) asm volatile("s_waitcnt vmcnt(6)" ::: "memory");
            else            asm volatile("s_waitcnt vmcnt(0)" ::: "memory");
            __builtin_amdgcn_sched_barrier(0);
            __builtin_amdgcn_s_barrier();
            __builtin_amdgcn_sched_barrier(0);

            const unsigned short* As = lds + (t % 3) * BUFE;
            const unsigned short* Bs = As + ABUF;
            unsigned short* nbuf = lds + ((t + 2) % 3) * BUFE;
            const bool st = (t + 2 < NT);
            const int k2 = (t + 2) * P_BK;

            if (st) stage_part<0, 2>(Ag, K, k2, nbuf, tid);

            short8 bf[4][2];
#pragma unroll
            for (int n = 0; n < 4; ++n)
#pragma unroll
                for (int s = 0; s < 2; ++s)
                    bf[n][s] = lfrag(Bs, brow + n * 16, s * 64 + hi * 16);
            short8 af0[2][2];
#pragma unroll
            for (int m = 0; m < 2; ++m)
#pragma unroll
                for (int s = 0; s < 2; ++s)
                    af0[m][s] = lfrag(As, arow + m * 16, s * 64 + hi * 16);

            if (st) stage_part<2, 4>(Ag, K, k2, nbuf, tid);

            __builtin_amdgcn_s_setprio(1);
#pragma unroll
            for (int m = 0; m < 2; ++m)
#pragma unroll
                for (int n = 0; n < 4; ++n)
#pragma unroll
                    for (int s = 0; s < 2; ++s)
                        acc[m][n] = __builtin_amdgcn_mfma_f32_16x16x32_bf16(af0[m][s], bf[n][s], acc[m][n], 0, 0, 0);
            __builtin_amdgcn_s_setprio(0);

            short8 af1[2][2];
#pragma unroll
            for (int m = 0; m < 2; ++m)
#pragma unroll
                for (int s = 0; s < 2; ++s)
                    af1[m][s] = lfrag(As, arow + 32 + m * 16, s * 64 + hi * 16);

            if (st) stage_part<0, 2>(Bg, K, k2, nbuf + ABUF, tid);

            __builtin_amdgcn_s_setprio(1);
#pragma unroll
            for (int m = 0; m < 2; ++m)
#pragma unroll
                for (int n = 0; n < 4; ++n)
#pragma unroll
                    for (int s = 0; s < 2; ++s)
                        acc[2 + m][n] = __builtin_amdgcn_mfma_f32_16x16x32_bf16(af1[m][s], bf[n][s], acc[2 + m][n], 0, 0, 0);
            __builtin_amdgcn_s_setprio(0);
        }

#pragma unroll
        for (int m = 0; m < 4; ++m) {
            int rg = row0 + wm * 64 + m * 16 + hi * 4;
#pragma unroll
            for (int n = 0; n < 4; ++n) {
                int cg = col0 + wn * 64 + n * 16 + lr;
#pragma unroll
                for (int j = 0; j < 4; ++j)
                    C[(size_t)(rg + j) * N + cg] = f32_to_bf16(acc[m][n][j]);
            }
        }
    } else {
        // ---- convert waves: 512 threads, 32 iters x 2 chunks x 8 elems = 64M total ----
        const int ct = tid - 512;
        for (int t = 0; t < NT; ++t) {
#pragma unroll
            for (int j = 0; j < 2; ++j) {
                const size_t idx = (((size_t)t * 256 + bid) * 2 + j) * 4096 + (size_t)ct * 8;
                f32x4 v0 = *(const f32x4*)(feats + idx);
                f32x4 v1 = *(const f32x4*)(feats + idx + 4);
                short8 h;
#pragma unroll
                for (int q = 0; q < 4; ++q) h[q] = (short)f32_to_bf16(v0[q]);
#pragma unroll
                for (int q = 0; q < 4; ++q) h[4 + q] = (short)f32_to_bf16(v1[q]);
                *(short8*)(featsB + idx) = h;
            }
            __builtin_amdgcn_s_barrier();
        }
    }
}

// ---------------- GEMM2 (R7-proven, unchanged): 256x128, 3-buf, chunked XCD row-panels ----------
__global__ __launch_bounds__(512) void gemm2_p(
    const unsigned short* __restrict__ A, const unsigned short* __restrict__ Bt,
    const float* __restrict__ bias, float* __restrict__ out,
    int M, int N, int K, int Nout) {
    extern __shared__ unsigned short lds[];
    const int bid = blockIdx.x;
    const int x = bid & 7, i = bid >> 3;
    const int row0 = (x * 4 + (i >> 3)) * P_BM;
    const int col0 = (i & 7) * P_BN;
    const int tid = threadIdx.x;
    const int w = tid >> 6, lane = tid & 63;
    const int wm = w >> 1, wn = w & 1;
    const int lr = lane & 15, hi = lane >> 4;
    const int arow = wm * 64 + lr;
    const int brow = wn * 64 + lr;

    const unsigned short* Ag = A + (size_t)row0 * K;
    const unsigned short* Bg = Bt + (size_t)col0 * K;

    f32x4 acc[4][4];
#pragma unroll
    for (int m = 0; m < 4; ++m)
#pragma unroll
        for (int n = 0; n < 4; ++n) acc[m][n] = (f32x4){0.f, 0.f, 0.f, 0.f};

    const int NT = K / P_BK;
    stage_part<0, 4>(Ag, K, 0, lds, tid);
    stage_part<0, 2>(Bg, K, 0, lds + ABUF, tid);
    stage_part<0, 4>(Ag, K, P_BK, lds + BUFE, tid);
    stage_part<0, 2>(Bg, K, P_BK, lds + BUFE + ABUF, tid);

    for (int t = 0; t < NT; ++t) {
        if (t + 1 < NT) asm volatile("s_waitcnt vmcnt(6)" ::: "memory");
        else            asm volatile("s_waitcnt vmcnt(0)" ::: "memory");
        __builtin_amdgcn_sched_barrier(0);
        __builtin_amdgcn_s_barrier();
        __builtin_amdgcn_sched_barrier(0);

        const unsigned short* As = lds + (t % 3) * BUFE;
        const unsigned short* Bs = As + ABUF;
        unsigned short* nbuf = lds + ((t + 2) % 3) * BUFE;
        const bool st = (t + 2 < NT);
        const int k2 = (t + 2) * P_BK;

        if (st) stage_part<0, 2>(Ag, K, k2, nbuf, tid);

        short8 bf[4][2];
#pragma unroll
        for (int n = 0; n < 4; ++n)
#pragma unroll
            for (int s = 0; s < 2; ++s)
                bf[n][s] = lfrag(Bs, brow + n * 16, s * 64 + hi * 16);
        short8 af0[2][2];
#pragma unroll
        for (int m = 0; m < 2; ++m)
#pragma unroll
            for (int s = 0; s < 2; ++s)
                af0[m][s] = lfrag(As, arow + m * 16, s * 64 + hi * 16);

        if (st) stage_part<2, 4>(Ag, K, k2, nbuf, tid);

        __builtin_amdgcn_s_setprio(1);
#pragma unroll
        for (int m = 0; m < 2; ++m)
#pragma unroll
            for (int n = 0; n < 4; ++n)
#pragma unroll
                for (int s = 0; s < 2; ++s)
                    acc[m][n] = __builtin_amdgcn_mfma_f32_16x16x32_bf16(af0[m][s], bf[n][s], acc[m][n], 0, 0, 0);
        __builtin_amdgcn_s_setprio(0);

        short8 af1[2][2];
#pragma unroll
        for (int m = 0; m < 2; ++m)
#pragma unroll
            for (int s = 0; s < 2; ++s)
                af1[m][s] = lfrag(As, arow + 32 + m * 16, s * 64 + hi * 16);

        if (st) stage_part<0, 2>(Bg, K, k2, nbuf + ABUF, tid);

        __builtin_amdgcn_s_setprio(1);
#pragma unroll
        for (int m = 0; m < 2; ++m)
#pragma unroll
            for (int n = 0; n < 4; ++n)
#pragma unroll
                for (int s = 0; s < 2; ++s)
                    acc[2 + m][n] = __builtin_amdgcn_mfma_f32_16x16x32_bf16(af1[m][s], bf[n][s], acc[2 + m][n], 0, 0, 0);
        __builtin_amdgcn_s_setprio(0);
    }

#pragma unroll
    for (int m = 0; m < 4; ++m) {
        int rg = row0 + wm * 64 + m * 16 + hi * 4;
#pragma unroll
        for (int n = 0; n < 4; ++n) {
            int cg = col0 + wn * 64 + n * 16 + lr;
            if (cg < Nout) {
                float bv = bias[cg];
#pragma unroll
                for (int j = 0; j < 4; ++j)
                    out[(size_t)(rg + j) * Nout + cg] = acc[m][n][j] + bv;
            }
        }
    }
}

extern "C" void kernel_launch(void* const* d_in, const int* in_sizes, int n_in,
                              void* d_out, int out_size, void* d_ws, size_t ws_size,
                              hipStream_t stream) {
    const float* feats = (const float*)d_in[0];   // [8192][8192]
    const float* mean  = (const float*)d_in[1];   // [8192]
    const float* comp  = (const float*)d_in[2];   // [2048][8192]
    const float* W     = (const float*)d_in[3];   // [2048][1000]
    float* out = (float*)d_out;                   // [8192][1000]

    const int N = 8192, D = 8192, Kp = 2048, C = 1000, Cp = 1024;

    char* ws = (char*)d_ws;
    unsigned short* Wt    = (unsigned short*)ws;                  // [Cp][Kp]   4 MB
    size_t off = (size_t)Cp * Kp * 2;
    unsigned short* compT = (unsigned short*)(ws + off);          // [D][Kp]   32 MB
    off += (size_t)D * Kp * 2;
    unsigned short* Mt    = (unsigned short*)(ws + off);          // [Cp][D]   16 MB
    off += (size_t)Cp * D * 2;
    float* bias           = (float*)(ws + off);                   // [Cp]
    off += 4096;
    unsigned short* featsB = (unsigned short*)(ws + off);         // [N][D]   128 MB

    // merged transposes: W (512 blocks) + comp (4096 blocks), one launch
    transpose_both<<<WT_BLOCKS + (D / 64) * (Kp / 64), 256, 0, stream>>>(W, Wt, comp, compT);

    hipFuncSetAttribute(reinterpret_cast<const void*>(fat_g1conv),
                        hipFuncAttributeMaxDynamicSharedMemorySize, P_LDS_BYTES);
    hipFuncSetAttribute(reinterpret_cast<const void*>(gemm2_p),
                        hipFuncAttributeMaxDynamicSharedMemorySize, P_LDS_BYTES);

    // FAT: GEMM1 (waves 0-7, pipelined) || feats convert (waves 8-15); grid 256 = 1/CU
    fat_g1conv<<<(Cp / P_BM) * (D / P_BN), 1024, P_LDS_BYTES, stream>>>(
        Wt, compT, Mt, Cp, D, Kp, feats, featsB);

    bias_kernel<<<Cp, 256, 0, stream>>>(mean, Mt, bias, D);

    // GEMM2: out[8192][1000] = featsB @ Mt^T + bias ; grid 32x8 = 256 = 1/CU
    gemm2_p<<<(N / P_BM) * (Cp / P_BN), 512, P_LDS_BYTES, stream>>>(
        featsB, Mt, bias, out, N, Cp, D, C);
}

// Round 15
// 257.886 us; speedup vs baseline: 1.5055x; 1.5055x over previous
//
#include <hip/hip_runtime.h>
#include <hip/hip_bf16.h>

typedef __attribute__((ext_vector_type(4))) float  f32x4;
typedef __attribute__((ext_vector_type(8))) short  short8;
typedef __attribute__((ext_vector_type(4))) short  short4v;

__device__ __forceinline__ unsigned short f32_to_bf16(float f) {
    union { float f; unsigned u; } v; v.f = f;
    unsigned r = v.u + 0x7FFFu + ((v.u >> 16) & 1u);   // RNE
    return (unsigned short)(r >> 16);
}
__device__ __forceinline__ float bf16_to_f32(unsigned short h) {
    union { unsigned u; float f; } v; v.u = ((unsigned)h) << 16; return v.f;
}
__device__ __forceinline__ void gload_lds16(const void* g, void* l) {
    __builtin_amdgcn_global_load_lds(
        (const __attribute__((address_space(1))) unsigned int*)g,
        (__attribute__((address_space(3))) unsigned int*)l,
        16, 0, 0);
}

// ---------------- transpose + fp32->bf16 convert ----------------
__global__ __launch_bounds__(256) void transpose_to_bf16(
    const float* __restrict__ src, unsigned short* __restrict__ dst,
    int R, int Cin, int Cpad) {
    __shared__ float tile[32][33];
    const int tx = threadIdx.x, ty = threadIdx.y;
    const int c0 = blockIdx.x * 32, r0 = blockIdx.y * 32;
#pragma unroll
    for (int i = 0; i < 4; ++i) {
        int r = r0 + ty + i * 8, c = c0 + tx;
        float v = 0.f;
        if (r < R && c < Cin) v = src[(size_t)r * Cin + c];
        tile[ty + i * 8][tx] = v;
    }
    __syncthreads();
#pragma unroll
    for (int i = 0; i < 4; ++i) {
        int c = c0 + ty + i * 8, r = r0 + tx;
        if (c < Cpad && r < R)
            dst[(size_t)c * R + r] = f32_to_bf16(tile[tx][ty + i * 8]);
    }
}

// ---------------- bias[c] = -sum_d mean[d] * Mt[c][d] ----------------
__global__ __launch_bounds__(256) void bias_kernel(
    const float* __restrict__ mean, const unsigned short* __restrict__ Mt,
    float* __restrict__ bias, int D) {
    const int c = blockIdx.x;
    const unsigned short* row = Mt + (size_t)c * D;
    float s = 0.f;
    for (int d0 = threadIdx.x * 8; d0 < D; d0 += 256 * 8) {
        short4v h0 = *(const short4v*)&row[d0];
        short4v h1 = *(const short4v*)&row[d0 + 4];
        f32x4  m0 = *(const f32x4*)&mean[d0];
        f32x4  m1 = *(const f32x4*)&mean[d0 + 4];
#pragma unroll
        for (int j = 0; j < 4; ++j) {
            s += bf16_to_f32((unsigned short)h0[j]) * m0[j];
            s += bf16_to_f32((unsigned short)h1[j]) * m1[j];
        }
    }
#pragma unroll
    for (int off = 32; off > 0; off >>= 1) s += __shfl_down(s, off);
    __shared__ float red[4];
    const int lane = threadIdx.x & 63, w = threadIdx.x >> 6;
    if (lane == 0) red[w] = s;
    __syncthreads();
    if (threadIdx.x == 0) bias[c] = -(red[0] + red[1] + red[2] + red[3]);
}

// ================= shared staging helpers (swizzle: byte ^= (row&7)<<4 in 128B rows) ===========
template<int P0, int P1>
__device__ __forceinline__ void stage_part(
    const unsigned short* __restrict__ g, int K, int k0,
    unsigned short* l, int tid) {
#pragma unroll
    for (int p = P0; p < P1; ++p) {
        unsigned lin = ((unsigned)p * 512 + (unsigned)tid) * 16u;
        unsigned row = lin >> 7;
        unsigned colb = (lin ^ ((row & 7u) << 4)) & 127u;
        gload_lds16((const char*)g + (size_t)row * K * 2 + (size_t)k0 * 2 + colb,
                    (char*)l + lin);
    }
}

__device__ __forceinline__ short8 lfrag(const unsigned short* base, unsigned row, unsigned cb) {
    unsigned lin = row * 128u + cb;
    unsigned b = lin ^ ((row & 7u) << 4);
    return *(const short8*)((const char*)base + b);
}

// ================= FAT: waves 0-7 pipelined GEMM1 (256x128, 3-buf) ; waves 8-11 convert =========
// 768 threads = 12 waves/block = 3 waves/SIMD -> VGPR cap 128 >= ~80 needed (NO spill).
// [R14 lesson: 1024 threads caps VGPR at 64 -> GEMM spills -> 2.6x slowdown. Keep 768.]
#define P_BM 256
#define P_BN 128
#define P_BK 64
#define ABUF 16384
#define BUFE 24576
#define P_LDS_BYTES (3 * BUFE * 2)

__global__ __launch_bounds__(768) void fat_g1conv(
    const unsigned short* __restrict__ A, const unsigned short* __restrict__ Bt,
    unsigned short* __restrict__ C, int M, int N, int K,
    const float* __restrict__ feats, unsigned short* __restrict__ featsB) {
    extern __shared__ unsigned short lds[];
    const int bid = blockIdx.x;
    const int tid = threadIdx.x;
    const int NT = K / P_BK;                     // 32

    if (tid < 512) {
        const int x = bid & 7, i = bid >> 3;
        const int col0 = (x * 8 + (i >> 2)) * P_BN;
        const int row0 = (i & 3) * P_BM;
        const int w = tid >> 6, lane = tid & 63;
        const int wm = w >> 1, wn = w & 1;
        const int lr = lane & 15, hi = lane >> 4;
        const int arow = wm * 64 + lr;
        const int brow = wn * 64 + lr;

        const unsigned short* Ag = A + (size_t)row0 * K;
        const unsigned short* Bg = Bt + (size_t)col0 * K;

        f32x4 acc[4][4];
#pragma unroll
        for (int m = 0; m < 4; ++m)
#pragma unroll
            for (int n = 0; n < 4; ++n) acc[m][n] = (f32x4){0.f, 0.f, 0.f, 0.f};

        stage_part<0, 4>(Ag, K, 0, lds, tid);
        stage_part<0, 2>(Bg, K, 0, lds + ABUF, tid);
        stage_part<0, 4>(Ag, K, P_BK, lds + BUFE, tid);
        stage_part<0, 2>(Bg, K, P_BK, lds + BUFE + ABUF, tid);

        for (int t = 0; t < NT; ++t) {
            if (t + 1 < NT) asm volatile("s_waitcnt vmcnt(6)" ::: "memory");
            else            asm volatile("s_waitcnt vmcnt(0)" ::: "memory");
            __builtin_amdgcn_sched_barrier(0);
            __builtin_amdgcn_s_barrier();
            __builtin_amdgcn_sched_barrier(0);

            const unsigned short* As = lds + (t % 3) * BUFE;
            const unsigned short* Bs = As + ABUF;
            unsigned short* nbuf = lds + ((t + 2) % 3) * BUFE;
            const bool st = (t + 2 < NT);
            const int k2 = (t + 2) * P_BK;

            if (st) stage_part<0, 2>(Ag, K, k2, nbuf, tid);

            short8 bf[4][2];
#pragma unroll
            for (int n = 0; n < 4; ++n)
#pragma unroll
                for (int s = 0; s < 2; ++s)
                    bf[n][s] = lfrag(Bs, brow + n * 16, s * 64 + hi * 16);
            short8 af0[2][2];
#pragma unroll
            for (int m = 0; m < 2; ++m)
#pragma unroll
                for (int s = 0; s < 2; ++s)
                    af0[m][s] = lfrag(As, arow + m * 16, s * 64 + hi * 16);

            if (st) stage_part<2, 4>(Ag, K, k2, nbuf, tid);

            __builtin_amdgcn_s_setprio(1);
#pragma unroll
            for (int m = 0; m < 2; ++m)
#pragma unroll
                for (int n = 0; n < 4; ++n)
#pragma unroll
                    for (int s = 0; s < 2; ++s)
                        acc[m][n] = __builtin_amdgcn_mfma_f32_16x16x32_bf16(af0[m][s], bf[n][s], acc[m][n], 0, 0, 0);
            __builtin_amdgcn_s_setprio(0);

            short8 af1[2][2];
#pragma unroll
            for (int m = 0; m < 2; ++m)
#pragma unroll
                for (int s = 0; s < 2; ++s)
                    af1[m][s] = lfrag(As, arow + 32 + m * 16, s * 64 + hi * 16);

            if (st) stage_part<0, 2>(Bg, K, k2, nbuf + ABUF, tid);

            __builtin_amdgcn_s_setprio(1);
#pragma unroll
            for (int m = 0; m < 2; ++m)
#pragma unroll
                for (int n = 0; n < 4; ++n)
#pragma unroll
                    for (int s = 0; s < 2; ++s)
                        acc[2 + m][n] = __builtin_amdgcn_mfma_f32_16x16x32_bf16(af1[m][s], bf[n][s], acc[2 + m][n], 0, 0, 0);
            __builtin_amdgcn_s_setprio(0);
        }

#pragma unroll
        for (int m = 0; m < 4; ++m) {
            int rg = row0 + wm * 64 + m * 16 + hi * 4;
#pragma unroll
            for (int n = 0; n < 4; ++n) {
                int cg = col0 + wn * 64 + n * 16 + lr;
#pragma unroll
                for (int j = 0; j < 4; ++j)
                    C[(size_t)(rg + j) * N + cg] = f32_to_bf16(acc[m][n][j]);
            }
        }
    } else {
        const int ct = tid - 512;
        for (int t = 0; t < NT; ++t) {
            const size_t base = ((size_t)t * 256 + (size_t)bid) * 8192;
#pragma unroll
            for (int j = 0; j < 4; ++j) {
                const size_t idx = base + (size_t)j * 2048 + (size_t)ct * 8;
                f32x4 v0 = *(const f32x4*)(feats + idx);
                f32x4 v1 = *(const f32x4*)(feats + idx + 4);
                short8 h;
#pragma unroll
                for (int q = 0; q < 4; ++q) h[q] = (short)f32_to_bf16(v0[q]);
#pragma unroll
                for (int q = 0; q < 4; ++q) h[4 + q] = (short)f32_to_bf16(v1[q]);
                *(short8*)(featsB + idx) = h;
            }
            __builtin_amdgcn_s_barrier();
        }
    }
}

// ---------------- GEMM2 (R7-proven, unchanged): 256x128, 3-buf, chunked XCD row-panels ----------
__global__ __launch_bounds__(512) void gemm2_p(
    const unsigned short* __restrict__ A, const unsigned short* __restrict__ Bt,
    const float* __restrict__ bias, float* __restrict__ out,
    int M, int N, int K, int Nout) {
    extern __shared__ unsigned short lds[];
    const int bid = blockIdx.x;
    const int x = bid & 7, i = bid >> 3;
    const int row0 = (x * 4 + (i >> 3)) * P_BM;
    const int col0 = (i & 7) * P_BN;
    const int tid = threadIdx.x;
    const int w = tid >> 6, lane = tid & 63;
    const int wm = w >> 1, wn = w & 1;
    const int lr = lane & 15, hi = lane >> 4;
    const int arow = wm * 64 + lr;
    const int brow = wn * 64 + lr;

    const unsigned short* Ag = A + (size_t)row0 * K;
    const unsigned short* Bg = Bt + (size_t)col0 * K;

    f32x4 acc[4][4];
#pragma unroll
    for (int m = 0; m < 4; ++m)
#pragma unroll
        for (int n = 0; n < 4; ++n) acc[m][n] = (f32x4){0.f, 0.f, 0.f, 0.f};

    const int NT = K / P_BK;
    stage_part<0, 4>(Ag, K, 0, lds, tid);
    stage_part<0, 2>(Bg, K, 0, lds + ABUF, tid);
    stage_part<0, 4>(Ag, K, P_BK, lds + BUFE, tid);
    stage_part<0, 2>(Bg, K, P_BK, lds + BUFE + ABUF, tid);

    for (int t = 0; t < NT; ++t) {
        if (t + 1 < NT) asm volatile("s_waitcnt vmcnt(6)" ::: "memory");
        else            asm volatile("s_waitcnt vmcnt(0)" ::: "memory");
        __builtin_amdgcn_sched_barrier(0);
        __builtin_amdgcn_s_barrier();
        __builtin_amdgcn_sched_barrier(0);

        const unsigned short* As = lds + (t % 3) * BUFE;
        const unsigned short* Bs = As + ABUF;
        unsigned short* nbuf = lds + ((t + 2) % 3) * BUFE;
        const bool st = (t + 2 < NT);
        const int k2 = (t + 2) * P_BK;

        if (st) stage_part<0, 2>(Ag, K, k2, nbuf, tid);

        short8 bf[4][2];
#pragma unroll
        for (int n = 0; n < 4; ++n)
#pragma unroll
            for (int s = 0; s < 2; ++s)
                bf[n][s] = lfrag(Bs, brow + n * 16, s * 64 + hi * 16);
        short8 af0[2][2];
#pragma unroll
        for (int m = 0; m < 2; ++m)
#pragma unroll
            for (int s = 0; s < 2; ++s)
                af0[m][s] = lfrag(As, arow + m * 16, s * 64 + hi * 16);

        if (st) stage_part<2, 4>(Ag, K, k2, nbuf, tid);

        __builtin_amdgcn_s_setprio(1);
#pragma unroll
        for (int m = 0; m < 2; ++m)
#pragma unroll
            for (int n = 0; n < 4; ++n)
#pragma unroll
                for (int s = 0; s < 2; ++s)
                    acc[m][n] = __builtin_amdgcn_mfma_f32_16x16x32_bf16(af0[m][s], bf[n][s], acc[m][n], 0, 0, 0);
        __builtin_amdgcn_s_setprio(0);

        short8 af1[2][2];
#pragma unroll
        for (int m = 0; m < 2; ++m)
#pragma unroll
            for (int s = 0; s < 2; ++s)
                af1[m][s] = lfrag(As, arow + 32 + m * 16, s * 64 + hi * 16);

        if (st) stage_part<0, 2>(Bg, K, k2, nbuf + ABUF, tid);

        __builtin_amdgcn_s_setprio(1);
#pragma unroll
        for (int m = 0; m < 2; ++m)
#pragma unroll
            for (int n = 0; n < 4; ++n)
#pragma unroll
                for (int s = 0; s < 2; ++s)
                    acc[2 + m][n] = __builtin_amdgcn_mfma_f32_16x16x32_bf16(af1[m][s], bf[n][s], acc[2 + m][n], 0, 0, 0);
        __builtin_amdgcn_s_setprio(0);
    }

#pragma unroll
    for (int m = 0; m < 4; ++m) {
        int rg = row0 + wm * 64 + m * 16 + hi * 4;
#pragma unroll
        for (int n = 0; n < 4; ++n) {
            int cg = col0 + wn * 64 + n * 16 + lr;
            if (cg < Nout) {
                float bv = bias[cg];
#pragma unroll
                for (int j = 0; j < 4; ++j)
                    out[(size_t)(rg + j) * Nout + cg] = acc[m][n][j] + bv;
            }
        }
    }
}

extern "C" void kernel_launch(void* const* d_in, const int* in_sizes, int n_in,
                              void* d_out, int out_size, void* d_ws, size_t ws_size,
                              hipStream_t stream) {
    const float* feats = (const float*)d_in[0];   // [8192][8192]
    const float* mean  = (const float*)d_in[1];   // [8192]
    const float* comp  = (const float*)d_in[2];   // [2048][8192]
    const float* W     = (const float*)d_in[3];   // [2048][1000]
    float* out = (float*)d_out;                   // [8192][1000]

    const int N = 8192, D = 8192, Kp = 2048, C = 1000, Cp = 1024;

    char* ws = (char*)d_ws;
    unsigned short* Wt    = (unsigned short*)ws;                  // [Cp][Kp]   4 MB
    size_t off = (size_t)Cp * Kp * 2;
    unsigned short* compT = (unsigned short*)(ws + off);          // [D][Kp]   32 MB
    off += (size_t)D * Kp * 2;
    unsigned short* Mt    = (unsigned short*)(ws + off);          // [Cp][D]   16 MB
    off += (size_t)Cp * D * 2;
    float* bias           = (float*)(ws + off);                   // [Cp]
    off += 4096;
    unsigned short* featsB = (unsigned short*)(ws + off);         // [N][D]   128 MB

    dim3 tb(32, 8);
    transpose_to_bf16<<<dim3(Cp / 32, Kp / 32), tb, 0, stream>>>(W, Wt, Kp, C, Cp);
    transpose_to_bf16<<<dim3(D / 32, Kp / 32), tb, 0, stream>>>(comp, compT, Kp, D, D);

    hipFuncSetAttribute(reinterpret_cast<const void*>(fat_g1conv),
                        hipFuncAttributeMaxDynamicSharedMemorySize, P_LDS_BYTES);
    hipFuncSetAttribute(reinterpret_cast<const void*>(gemm2_p),
                        hipFuncAttributeMaxDynamicSharedMemorySize, P_LDS_BYTES);

    // FAT: GEMM1 (waves 0-7, pipelined) || feats convert (waves 8-11); grid 256 = 1/CU
    fat_g1conv<<<(Cp / P_BM) * (D / P_BN), 768, P_LDS_BYTES, stream>>>(
        Wt, compT, Mt, Cp, D, Kp, feats, featsB);

    bias_kernel<<<Cp, 256, 0, stream>>>(mean, Mt, bias, D);

    // GEMM2: out[8192][1000] = featsB @ Mt^T + bias ; grid 32x8 = 256 = 1/CU
    gemm2_p<<<(N / P_BM) * (Cp / P_BN), 512, P_LDS_BYTES, stream>>>(
        featsB, Mt, bias, out, N, Cp, D, C);
}